// Round 2
// baseline (824.808 us; speedup 1.0000x reference)
//
#include <hip/hip_runtime.h>

#define KOFF 9
#define N_PTS 262144
#define D 32
#define THREADS 256
#define ROW_MASK 0x3ffff   // N_PTS = 2^18

// ---------------- out[n][d] = bias[d] ----------------
__global__ void bias_init_kernel(const float* __restrict__ bias,
                                 float* __restrict__ out) {
    int i = blockIdx.x * blockDim.x + threadIdx.x;   // one float4 per thread
    float4 b = ((const float4*)bias)[i & 7];
    ((float4*)out)[i] = b;
}

// ---------------- Path A: bucket inversion ----------------
// One thread per (k,p) pair: claim a slot in the output row's bucket.
// Bucket entry = irow | (k << 18). Overflow (slot >= cap) is rare
// (Poisson(4.5) tail): compute the contribution directly with atomics.
__global__ void __launch_bounds__(THREADS)
fill_kernel(const int* __restrict__ indice_pairs,
            const int* __restrict__ indice_pair_num,
            const float* __restrict__ feat,
            const float* __restrict__ weight,
            int* __restrict__ counts,
            unsigned int* __restrict__ buckets,
            float* __restrict__ out,
            int cap) {
    const int k   = blockIdx.y;
    const int n_k = indice_pair_num[k];
    if (blockIdx.x * THREADS >= n_k) return;          // whole block idle
    const int p = blockIdx.x * THREADS + threadIdx.x;
    if (p >= n_k) return;

    int irow = indice_pairs[(size_t)k * N_PTS + p];
    int orow = indice_pairs[(size_t)(KOFF + k) * N_PTS + p];
    int slot = atomicAdd(&counts[orow], 1);
    if (slot < cap) {
        buckets[(size_t)orow * cap + slot] =
            (unsigned int)irow | ((unsigned int)k << 18);
    } else {
        // rare overflow: direct scatter-add of this pair's contribution
        float fr[D];
#pragma unroll
        for (int c = 0; c < D; c += 4)
            *(float4*)&fr[c] = *(const float4*)&feat[(size_t)irow * D + c];
#pragma unroll 1
        for (int dd = 0; dd < D; ++dd) {
            float a = 0.f;
#pragma unroll
            for (int c = 0; c < D; ++c)
                a += fr[c] * weight[dd * (KOFF * D) + k * D + c];
            atomicAdd(&out[(size_t)orow * D + dd], a);
        }
    }
}

// 32 lanes per output row; 8 rows per block. Gather entries, broadcast
// feat values via shfl(width=32), FMA vs LDS weights, ONE store per row.
__global__ void __launch_bounds__(THREADS)
gather_compute_kernel(const float* __restrict__ feat,
                      const float* __restrict__ weight,
                      const int* __restrict__ counts,
                      const unsigned int* __restrict__ buckets,
                      float* __restrict__ out,
                      int cap) {
    __shared__ float w[KOFF][D][D];                   // w[k][c][d], 36 KB
    for (int idx = threadIdx.x; idx < KOFF * D * D; idx += THREADS) {
        int k = idx >> 10, rem = idx & 1023, c = rem >> 5, d = rem & 31;
        w[k][c][d] = weight[d * (KOFF * D) + k * D + c];
    }
    __syncthreads();

    const int r = blockIdx.x * (THREADS / 32) + (threadIdx.x >> 5);
    const int d = threadIdx.x & 31;
    int cnt = counts[r];
    cnt = cnt < cap ? cnt : cap;

    float acc = out[(size_t)r * D + d];               // bias (+ overflow adds)
    const size_t base = (size_t)r * cap;

    unsigned int ent = 0; float f = 0.f;              // depth-1 pipeline
    if (cnt > 0) {
        ent = buckets[base];
        f   = feat[(size_t)(ent & ROW_MASK) * D + d]; // coalesced 128B/row
    }
    for (int e = 0; e < cnt; ++e) {
        unsigned int ec = ent; float fc = f;
        if (e + 1 < cnt) {
            ent = buckets[base + e + 1];
            f   = feat[(size_t)(ent & ROW_MASK) * D + d];
        }
        const float* wk = &w[ec >> 18][0][0];
#pragma unroll
        for (int c = 0; c < D; ++c)
            acc += __shfl(fc, c, 32) * wk[c * D + d]; // LDS banks 0..31, clean
    }
    out[(size_t)r * D + d] = acc;                     // single coalesced store
}

// ---------------- Path B fallback (R1 kernel) ----------------
#define PPB 8
__global__ void __launch_bounds__(THREADS)
scatter_conv_kernel(const float* __restrict__ feat,
                    const float* __restrict__ weight,
                    const int* __restrict__ indice_pairs,
                    const int* __restrict__ indice_pair_num,
                    float* __restrict__ out) {
    const int k   = blockIdx.y;
    const int n_k = indice_pair_num[k];
    const int p0  = blockIdx.x * PPB;
    if (p0 >= n_k) return;

    __shared__ float w[D][D];
    __shared__ float f[PPB][D];
    for (int idx = threadIdx.x; idx < D * D; idx += THREADS) {
        int c = idx >> 5, d = idx & 31;
        w[c][d] = weight[d * (KOFF * D) + k * D + c];
    }
    const int pp = threadIdx.x >> 5;
    const int d  = threadIdx.x & 31;
    const int p  = p0 + pp;
    const int* in_idx  = indice_pairs + (size_t)k * N_PTS;
    const int* out_idx = indice_pairs + (size_t)(KOFF + k) * N_PTS;
    int orow = -1;
    if (p < n_k) {
        int irow = in_idx[p];
        orow     = out_idx[p];
        f[pp][d] = feat[(size_t)irow * D + d];
    }
    __syncthreads();
    if (p < n_k) {
        float acc = 0.f;
#pragma unroll
        for (int c = 0; c < D; ++c)
            acc += f[pp][c] * w[c][d];
        atomicAdd(&out[(size_t)orow * D + d], acc);
    }
}

extern "C" void kernel_launch(void* const* d_in, const int* in_sizes, int n_in,
                              void* d_out, int out_size, void* d_ws, size_t ws_size,
                              hipStream_t stream) {
    const float* feat            = (const float*)d_in[0];
    const float* weight          = (const float*)d_in[1];
    const float* bias            = (const float*)d_in[2];
    const int*   indice_pairs    = (const int*)d_in[3];
    const int*   indice_pair_num = (const int*)d_in[4];
    float*       out             = (float*)d_out;

    int n_vec4 = N_PTS * D / 4;
    bias_init_kernel<<<n_vec4 / 256, 256, 0, stream>>>(bias, out);

    const size_t cnt_bytes = (size_t)N_PTS * 4;
    int cap = 0;
    if (ws_size > cnt_bytes) {
        size_t avail = (ws_size - cnt_bytes) / ((size_t)N_PTS * 4);
        cap = avail > 16 ? 16 : (int)avail;
    }

    if (cap >= 4) {
        int*          counts  = (int*)d_ws;
        unsigned int* buckets = (unsigned int*)((char*)d_ws + cnt_bytes);
        hipMemsetAsync(counts, 0, cnt_bytes, stream);
        dim3 fgrid(N_PTS / THREADS, KOFF);
        fill_kernel<<<fgrid, THREADS, 0, stream>>>(
            indice_pairs, indice_pair_num, feat, weight, counts, buckets, out, cap);
        gather_compute_kernel<<<N_PTS / (THREADS / 32), THREADS, 0, stream>>>(
            feat, weight, counts, buckets, out, cap);
    } else {
        dim3 grid((N_PTS + PPB - 1) / PPB, KOFF);
        scatter_conv_kernel<<<grid, THREADS, 0, stream>>>(
            feat, weight, indice_pairs, indice_pair_num, out);
    }
}

// Round 4
// 414.489 us; speedup vs baseline: 1.9899x; 1.9899x over previous
//
#include <hip/hip_runtime.h>

#define KOFF 9
#define N_PTS 262144
#define D 32
#define BINS 256
#define ROWS_PER_BIN 1024      // N_PTS / BINS
#define TILE_ROWS 1025         // + dump row for tail/sentinel entries
#define CAP 1152               // per (bin,k) bucket capacity
#define OVER_CAP 524288
#define SENT (1024u << 18)

typedef __attribute__((ext_vector_type(4))) float f32x4;
typedef __attribute__((ext_vector_type(8))) short short8;
typedef __attribute__((ext_vector_type(4))) short short4v;

__device__ inline short f2bf(float f) {      // round-to-nearest-even f32->bf16
    unsigned u = __float_as_uint(f);
    u = (u + 0x7fffu + ((u >> 16) & 1u)) >> 16;
    return (short)u;
}

// ---------- fill: bin pairs by (orow>>10, k) ----------
__global__ void __launch_bounds__(256)
fill_kernel(const int* __restrict__ indice_pairs,
            const int* __restrict__ indice_pair_num,
            int* __restrict__ counts,          // [BINS*KOFF]
            unsigned int* __restrict__ buckets,
            uint2* __restrict__ overlist,
            int* __restrict__ over_n) {
    const int k = blockIdx.y;
    const int n_k = indice_pair_num[k];
    if (blockIdx.x * 256 >= n_k) return;
    const int p = blockIdx.x * 256 + threadIdx.x;
    if (p >= n_k) return;
    int irow = indice_pairs[(size_t)k * N_PTS + p];
    int orow = indice_pairs[(size_t)(KOFF + k) * N_PTS + p];
    int bin = orow >> 10, olow = orow & 1023;
    int b = bin * KOFF + k;
    int slot = atomicAdd(&counts[b], 1);
    if (slot < CAP) {
        buckets[(size_t)b * CAP + slot] = (unsigned)irow | ((unsigned)olow << 18);
    } else {
        int s2 = atomicAdd(over_n, 1);
        if (s2 < OVER_CAP) overlist[s2] = make_uint2((unsigned)irow | ((unsigned)k << 18),
                                                     (unsigned)orow);
    }
}

// ---------- phase 2: per-bin LDS-tile accumulate with MFMA ----------
__global__ void __launch_bounds__(512)
phase2_kernel(const float* __restrict__ feat,
              const float* __restrict__ weight,
              const float* __restrict__ bias,
              const int* __restrict__ counts,
              const unsigned int* __restrict__ buckets,
              float* __restrict__ out) {
    __shared__ f32x4 tile4[TILE_ROWS * D / 4];      // 131,200 B accumulator
    __shared__ short stage[8 * 16 * 40];            // 8 waves * 16 rows * 80 B
    float* tile = (float*)tile4;

    const int bin  = blockIdx.x;
    const int tid  = threadIdx.x;
    const int wave = tid >> 6;
    const int lane = tid & 63;

    // zero the tile
    f32x4 z = {0.f, 0.f, 0.f, 0.f};
    for (int i = tid; i < TILE_ROWS * D / 4; i += 512) tile4[i] = z;
    __syncthreads();

    short* swave = stage + wave * 640;              // 16 rows * 80 B stride

#pragma unroll 1
    for (int k = 0; k < KOFF; ++k) {
        // B fragments for this k, both dout halves:
        // B[c=(lane>>4)*8+j][col=(lane&15)+16h] = weight[col][k][c]
        short8 bf0, bf1;
        {
            const float* wp0 = weight + (size_t)(lane & 15) * (KOFF * D)
                               + k * D + ((lane >> 4) << 3);
            const float* wp1 = wp0 + 16 * (KOFF * D);
            f32x4 w0 = *(const f32x4*)wp0;
            f32x4 w1 = *(const f32x4*)(wp0 + 4);
            f32x4 w2 = *(const f32x4*)wp1;
            f32x4 w3 = *(const f32x4*)(wp1 + 4);
#pragma unroll
            for (int j = 0; j < 4; ++j) {
                bf0[j] = f2bf(w0[j]); bf0[j + 4] = f2bf(w1[j]);
                bf1[j] = f2bf(w2[j]); bf1[j + 4] = f2bf(w3[j]);
            }
        }

        int cnt = counts[bin * KOFF + k];
        cnt = cnt < CAP ? cnt : CAP;
        const unsigned* bk = buckets + (size_t)(bin * KOFF + k) * CAP;
        int ngroups = (cnt + 15) >> 4;
#pragma unroll 1
        for (int g = wave; g < ngroups; g += 8) {
            int ei = g * 16 + (lane & 15);
            unsigned ent = (ei < cnt) ? bk[ei] : SENT;

            // gather 16 rows: lane covers row=lane>>2, f32 chunk q=lane&3
            int entg = __builtin_amdgcn_ds_bpermute((lane >> 2) << 2, (int)ent);
            int irow = entg & 0x3ffff;
            const float* fp = feat + ((size_t)irow << 5) + ((lane & 3) << 2);
            f32x4 f0 = *(const f32x4*)fp;           // c = q*4 .. +4
            f32x4 f1 = *(const f32x4*)(fp + 16);    // c = 16+q*4 .. +4

            short4v a0, a1;
#pragma unroll
            for (int j = 0; j < 4; ++j) { a0[j] = f2bf(f0[j]); a1[j] = f2bf(f1[j]); }
            short* sp = swave + (lane >> 2) * 40 + ((lane & 3) << 2);
            *(short4v*)sp = a0;
            *(short4v*)(sp + 16) = a1;

            // A fragment: row = lane&15, k-elems (lane>>4)*8..+8
            short8 af = *(short8*)(swave + (lane & 15) * 40 + ((lane >> 4) << 3));

            f32x4 acc0 = __builtin_amdgcn_mfma_f32_16x16x32_bf16(af, bf0, z, 0, 0, 0);
            f32x4 acc1 = __builtin_amdgcn_mfma_f32_16x16x32_bf16(af, bf1, z, 0, 0, 0);

            // scatter C: row=(lane>>4)*4+rg, col=lane&15 -> LDS atomic add
#pragma unroll
            for (int rg = 0; rg < 4; ++rg) {
                int crow = ((lane >> 4) << 2) + rg;
                int entc = __builtin_amdgcn_ds_bpermute(crow << 2, (int)ent);
                int rl = ((unsigned)entc >> 18) & 0x7ff;
                float* t = &tile[rl * D + (lane & 15)];
                atomicAdd(t, acc0[rg]);
                atomicAdd(t + 16, acc1[rg]);
            }
        }
    }
    __syncthreads();

    // stream tile + bias to out (coalesced, no atomics)
    f32x4 b4 = ((const f32x4*)bias)[tid & 7];
    for (int i = tid; i < ROWS_PER_BIN * 8; i += 512) {
        int row = i >> 3, c4 = i & 7;
        f32x4 v = *(f32x4*)&tile[row * D + c4 * 4];
        v += b4;
        *(f32x4*)&out[((size_t)(bin * ROWS_PER_BIN + row)) * D + c4 * 4] = v;
    }
}

// ---------- rare overflow cleanup (after phase2 store) ----------
__global__ void overflow_kernel(const float* __restrict__ feat,
                                const float* __restrict__ weight,
                                const uint2* __restrict__ overlist,
                                const int* __restrict__ over_n,
                                float* __restrict__ out) {
    int n = *over_n;
    n = n < OVER_CAP ? n : OVER_CAP;
    for (int i = blockIdx.x * blockDim.x + threadIdx.x; i < n;
         i += gridDim.x * blockDim.x) {
        uint2 e = overlist[i];
        int irow = e.x & 0x3ffff, k = (e.x >> 18) & 15, orow = (int)e.y;
        float fr[D];
#pragma unroll
        for (int c = 0; c < D; c += 4)
            *(f32x4*)&fr[c] = *(const f32x4*)&feat[(size_t)irow * D + c];
#pragma unroll 1
        for (int dd = 0; dd < D; ++dd) {
            float a = 0.f;
#pragma unroll
            for (int c = 0; c < D; ++c)
                a += fr[c] * weight[dd * (KOFF * D) + k * D + c];
            atomicAdd(&out[(size_t)orow * D + dd], a);
        }
    }
}

// ---------- fallback path (R1): direct scatter with global atomics ----------
__global__ void bias_init_kernel(const float* __restrict__ bias,
                                 float* __restrict__ out) {
    int i = blockIdx.x * blockDim.x + threadIdx.x;
    float4 b = ((const float4*)bias)[i & 7];
    ((float4*)out)[i] = b;
}

#define PPB 8
__global__ void __launch_bounds__(256)
scatter_conv_kernel(const float* __restrict__ feat,
                    const float* __restrict__ weight,
                    const int* __restrict__ indice_pairs,
                    const int* __restrict__ indice_pair_num,
                    float* __restrict__ out) {
    const int k   = blockIdx.y;
    const int n_k = indice_pair_num[k];
    const int p0  = blockIdx.x * PPB;
    if (p0 >= n_k) return;
    __shared__ float w[D][D];
    __shared__ float f[PPB][D];
    for (int idx = threadIdx.x; idx < D * D; idx += 256) {
        int c = idx >> 5, d = idx & 31;
        w[c][d] = weight[d * (KOFF * D) + k * D + c];
    }
    const int pp = threadIdx.x >> 5;
    const int d  = threadIdx.x & 31;
    const int p  = p0 + pp;
    int orow = -1;
    if (p < n_k) {
        int irow = indice_pairs[(size_t)k * N_PTS + p];
        orow     = indice_pairs[(size_t)(KOFF + k) * N_PTS + p];
        f[pp][d] = feat[(size_t)irow * D + d];
    }
    __syncthreads();
    if (p < n_k) {
        float acc = 0.f;
#pragma unroll
        for (int c = 0; c < D; ++c) acc += f[pp][c] * w[c][d];
        atomicAdd(&out[(size_t)orow * D + d], acc);
    }
}

extern "C" void kernel_launch(void* const* d_in, const int* in_sizes, int n_in,
                              void* d_out, int out_size, void* d_ws, size_t ws_size,
                              hipStream_t stream) {
    const float* feat            = (const float*)d_in[0];
    const float* weight          = (const float*)d_in[1];
    const float* bias            = (const float*)d_in[2];
    const int*   indice_pairs    = (const int*)d_in[3];
    const int*   indice_pair_num = (const int*)d_in[4];
    float*       out             = (float*)d_out;

    const size_t HDR   = 16384;                       // counts (9216 B) + over_n
    const size_t BKT   = (size_t)BINS * KOFF * CAP * 4;
    const size_t OVERB = (size_t)OVER_CAP * 8;
    const size_t need  = HDR + BKT + OVERB;

    if (ws_size >= need) {
        int*          counts   = (int*)d_ws;
        int*          over_n   = (int*)((char*)d_ws + 9216);
        unsigned int* buckets  = (unsigned int*)((char*)d_ws + HDR);
        uint2*        overlist = (uint2*)((char*)d_ws + HDR + BKT);

        hipMemsetAsync(d_ws, 0, HDR, stream);
        dim3 fgrid(N_PTS / 256, KOFF);
        fill_kernel<<<fgrid, 256, 0, stream>>>(indice_pairs, indice_pair_num,
                                               counts, buckets, overlist, over_n);
        phase2_kernel<<<BINS, 512, 0, stream>>>(feat, weight, bias, counts,
                                                buckets, out);
        overflow_kernel<<<64, 256, 0, stream>>>(feat, weight, overlist, over_n, out);
    } else {
        int n_vec4 = N_PTS * D / 4;
        bias_init_kernel<<<n_vec4 / 256, 256, 0, stream>>>(bias, out);
        dim3 grid((N_PTS + PPB - 1) / PPB, KOFF);
        scatter_conv_kernel<<<grid, 256, 0, stream>>>(
            feat, weight, indice_pairs, indice_pair_num, out);
    }
}

// Round 5
// 351.192 us; speedup vs baseline: 2.3486x; 1.1802x over previous
//
#include <hip/hip_runtime.h>

#define KOFF 9
#define N_PTS 262144
#define D 32
#define BINS 512
#define ROWS_PER_BIN 512       // N_PTS / BINS
#define TILE_ROWS 513          // + dump row for tail/sentinel entries
#define CAP 640                // per (bin,k) bucket capacity (mean<=512, +5.6 sigma)
#define OVER_CAP 524288
#define SENT (512u << 18)

typedef __attribute__((ext_vector_type(4))) float f32x4;
typedef __attribute__((ext_vector_type(8))) short short8;

__device__ inline short f2bf(float f) {      // round-to-nearest-even f32->bf16
    unsigned u = __float_as_uint(f);
    u = (u + 0x7fffu + ((u >> 16) & 1u)) >> 16;
    return (short)u;
}

// ---------- fill: bin pairs by (orow>>9, k); entry = irow | olow<<18 ----------
__global__ void __launch_bounds__(256)
fill_kernel(const int* __restrict__ indice_pairs,
            const int* __restrict__ indice_pair_num,
            int* __restrict__ counts,          // [BINS*KOFF]
            unsigned int* __restrict__ buckets,
            uint2* __restrict__ overlist,
            int* __restrict__ over_n) {
    const int k = blockIdx.y;
    const int n_k = indice_pair_num[k];
    if (blockIdx.x * 256 >= n_k) return;
    const int p = blockIdx.x * 256 + threadIdx.x;
    if (p >= n_k) return;
    int irow = indice_pairs[(size_t)k * N_PTS + p];
    int orow = indice_pairs[(size_t)(KOFF + k) * N_PTS + p];
    int bin = orow >> 9, olow = orow & 511;
    int b = bin * KOFF + k;
    int slot = atomicAdd(&counts[b], 1);
    if (slot < CAP) {
        buckets[(size_t)b * CAP + slot] = (unsigned)irow | ((unsigned)olow << 18);
    } else {
        int s2 = atomicAdd(over_n, 1);
        if (s2 < OVER_CAP) overlist[s2] = make_uint2((unsigned)irow | ((unsigned)k << 18),
                                                     (unsigned)orow);
    }
}

// ---------- phase 2: per-bin LDS-tile accumulate with MFMA ----------
// Tile swizzle: element (row, c) lives at row*32 + (c ^ (((row>>2)&1)<<4))
// -> ds-atomic scatter is 2-way (free) instead of 4-way banked.
__global__ void __launch_bounds__(512, 4)
phase2_kernel(const float* __restrict__ feat,
              const float* __restrict__ weight,
              const float* __restrict__ bias,
              const int* __restrict__ counts,
              const unsigned int* __restrict__ buckets,
              float* __restrict__ out) {
    __shared__ f32x4 tile4[TILE_ROWS * D / 4];      // 65,664 B accumulator
    float* tile = (float*)tile4;

    const int bin  = blockIdx.x;
    const int tid  = threadIdx.x;
    const int wave = tid >> 6;
    const int lane = tid & 63;

    f32x4 z = {0.f, 0.f, 0.f, 0.f};
    for (int i = tid; i < TILE_ROWS * D / 4; i += 512) tile4[i] = z;
    __syncthreads();

    const int arow = lane & 15;                     // this lane's A row / entry idx
    const int hoff = (lane >> 4) << 3;              // k-dim chunk: 8 floats

#pragma unroll 1
    for (int k = 0; k < KOFF; ++k) {
        // B fragments: B[c=hoff+j][col=arow(+16)] = weight[col][k][c]
        short8 bf0, bf1;
        {
            const float* wp0 = weight + (size_t)arow * (KOFF * D) + k * D + hoff;
            const float* wp1 = wp0 + 16 * (KOFF * D);
            f32x4 w0 = *(const f32x4*)wp0;
            f32x4 w1 = *(const f32x4*)(wp0 + 4);
            f32x4 w2 = *(const f32x4*)wp1;
            f32x4 w3 = *(const f32x4*)(wp1 + 4);
#pragma unroll
            for (int j = 0; j < 4; ++j) {
                bf0[j] = f2bf(w0[j]); bf0[j + 4] = f2bf(w1[j]);
                bf1[j] = f2bf(w2[j]); bf1[j + 4] = f2bf(w3[j]);
            }
        }

        int cnt = counts[bin * KOFF + k];
        cnt = cnt < CAP ? cnt : CAP;
        const unsigned* bk = buckets + (size_t)(bin * KOFF + k) * CAP;
        int ngroups = (cnt + 15) >> 4;

        // depth-2 pipeline: entry+feat for group g prefetched one iter ahead
        unsigned entA = SENT; f32x4 fa0 = z, fa1 = z;
        int g = wave;
        if (g < ngroups) {
            int ei = g * 16 + arow;
            entA = (ei < cnt) ? bk[ei] : SENT;
            const float* fp = feat + ((size_t)(entA & 0x3ffff) << 5) + hoff;
            fa0 = *(const f32x4*)fp; fa1 = *(const f32x4*)(fp + 4);
        }
#pragma unroll 1
        for (; g < ngroups; g += 8) {
            unsigned entB = SENT; f32x4 fb0 = z, fb1 = z;
            int gn = g + 8;
            if (gn < ngroups) {
                int ei = gn * 16 + arow;
                entB = (ei < cnt) ? bk[ei] : SENT;
                const float* fp = feat + ((size_t)(entB & 0x3ffff) << 5) + hoff;
                fb0 = *(const f32x4*)fp; fb1 = *(const f32x4*)(fp + 4);
            }

            short8 af;
#pragma unroll
            for (int j = 0; j < 4; ++j) { af[j] = f2bf(fa0[j]); af[j + 4] = f2bf(fa1[j]); }

            f32x4 acc0 = __builtin_amdgcn_mfma_f32_16x16x32_bf16(af, bf0, z, 0, 0, 0);
            f32x4 acc1 = __builtin_amdgcn_mfma_f32_16x16x32_bf16(af, bf1, z, 0, 0, 0);

            // scatter C: row=(lane>>4)*4+rg entries, cols arow & arow+16
#pragma unroll
            for (int rg = 0; rg < 4; ++rg) {
                int crow = ((lane >> 4) << 2) + rg;
                int entc = __builtin_amdgcn_ds_bpermute(crow << 2, (int)entA);
                int rl   = ((unsigned)entc >> 18) & 0x3ff;
                int sw   = ((rl >> 2) & 1) << 4;
                float* t = &tile[rl * D + (arow ^ sw)];
                atomicAdd(t, acc0[rg]);
                atomicAdd(&tile[rl * D + ((arow + 16) ^ sw)], acc1[rg]);
            }
            entA = entB; fa0 = fb0; fa1 = fb1;
        }
    }
    __syncthreads();

    // stream tile + bias to out (coalesced, unswizzled)
    f32x4 b4 = ((const f32x4*)bias)[tid & 7];
    for (int i = tid; i < ROWS_PER_BIN * 8; i += 512) {
        int row = i >> 3, c4 = i & 7;
        int sc4 = c4 ^ (((row >> 2) & 1) << 2);     // f32x4-level swizzle
        f32x4 v = tile4[row * 8 + sc4];
        v += b4;
        *(f32x4*)&out[((size_t)(bin * ROWS_PER_BIN + row)) * D + c4 * 4] = v;
    }
}

// ---------- rare overflow cleanup (after phase2 store) ----------
__global__ void overflow_kernel(const float* __restrict__ feat,
                                const float* __restrict__ weight,
                                const uint2* __restrict__ overlist,
                                const int* __restrict__ over_n,
                                float* __restrict__ out) {
    int n = *over_n;
    n = n < OVER_CAP ? n : OVER_CAP;
    for (int i = blockIdx.x * blockDim.x + threadIdx.x; i < n;
         i += gridDim.x * blockDim.x) {
        uint2 e = overlist[i];
        int irow = e.x & 0x3ffff, k = (e.x >> 18) & 15, orow = (int)e.y;
        float fr[D];
#pragma unroll
        for (int c = 0; c < D; c += 4)
            *(f32x4*)&fr[c] = *(const f32x4*)&feat[(size_t)irow * D + c];
#pragma unroll 1
        for (int dd = 0; dd < D; ++dd) {
            float a = 0.f;
#pragma unroll
            for (int c = 0; c < D; ++c)
                a += fr[c] * weight[dd * (KOFF * D) + k * D + c];
            atomicAdd(&out[(size_t)orow * D + dd], a);
        }
    }
}

// ---------- fallback path (R1): direct scatter with global atomics ----------
__global__ void bias_init_kernel(const float* __restrict__ bias,
                                 float* __restrict__ out) {
    int i = blockIdx.x * blockDim.x + threadIdx.x;
    float4 b = ((const float4*)bias)[i & 7];
    ((float4*)out)[i] = b;
}

#define PPB 8
__global__ void __launch_bounds__(256)
scatter_conv_kernel(const float* __restrict__ feat,
                    const float* __restrict__ weight,
                    const int* __restrict__ indice_pairs,
                    const int* __restrict__ indice_pair_num,
                    float* __restrict__ out) {
    const int k   = blockIdx.y;
    const int n_k = indice_pair_num[k];
    const int p0  = blockIdx.x * PPB;
    if (p0 >= n_k) return;
    __shared__ float w[D][D];
    __shared__ float f[PPB][D];
    for (int idx = threadIdx.x; idx < D * D; idx += 256) {
        int c = idx >> 5, d = idx & 31;
        w[c][d] = weight[d * (KOFF * D) + k * D + c];
    }
    const int pp = threadIdx.x >> 5;
    const int d  = threadIdx.x & 31;
    const int p  = p0 + pp;
    int orow = -1;
    if (p < n_k) {
        int irow = indice_pairs[(size_t)k * N_PTS + p];
        orow     = indice_pairs[(size_t)(KOFF + k) * N_PTS + p];
        f[pp][d] = feat[(size_t)irow * D + d];
    }
    __syncthreads();
    if (p < n_k) {
        float acc = 0.f;
#pragma unroll
        for (int c = 0; c < D; ++c) acc += f[pp][c] * w[c][d];
        atomicAdd(&out[(size_t)orow * D + d], acc);
    }
}

extern "C" void kernel_launch(void* const* d_in, const int* in_sizes, int n_in,
                              void* d_out, int out_size, void* d_ws, size_t ws_size,
                              hipStream_t stream) {
    const float* feat            = (const float*)d_in[0];
    const float* weight          = (const float*)d_in[1];
    const float* bias            = (const float*)d_in[2];
    const int*   indice_pairs    = (const int*)d_in[3];
    const int*   indice_pair_num = (const int*)d_in[4];
    float*       out             = (float*)d_out;

    const size_t HDR   = 32768;                       // counts (18,432 B) + over_n
    const size_t BKT   = (size_t)BINS * KOFF * CAP * 4;   // 11.25 MiB
    const size_t OVERB = (size_t)OVER_CAP * 8;            // 4 MiB
    const size_t need  = HDR + BKT + OVERB;               // ~15.3 MiB

    if (ws_size >= need) {
        int*          counts   = (int*)d_ws;
        int*          over_n   = (int*)((char*)d_ws + 20480);
        unsigned int* buckets  = (unsigned int*)((char*)d_ws + HDR);
        uint2*        overlist = (uint2*)((char*)d_ws + HDR + BKT);

        hipMemsetAsync(d_ws, 0, HDR, stream);
        dim3 fgrid(N_PTS / 256, KOFF);
        fill_kernel<<<fgrid, 256, 0, stream>>>(indice_pairs, indice_pair_num,
                                               counts, buckets, overlist, over_n);
        phase2_kernel<<<BINS, 512, 0, stream>>>(feat, weight, bias, counts,
                                                buckets, out);
        overflow_kernel<<<64, 256, 0, stream>>>(feat, weight, overlist, over_n, out);
    } else {
        int n_vec4 = N_PTS * D / 4;
        bias_init_kernel<<<n_vec4 / 256, 256, 0, stream>>>(bias, out);
        dim3 grid((N_PTS + PPB - 1) / PPB, KOFF);
        scatter_conv_kernel<<<grid, 256, 0, stream>>>(
            feat, weight, indice_pairs, indice_pair_num, out);
    }
}